// Round 6
// baseline (204.692 us; speedup 1.0000x reference)
//
#include <hip/hip_runtime.h>
#include <hip/hip_bf16.h>

// Pipeline (R13): wtrans -> fused(gemm||fill2) -> bucket_gather(512thr, shared sort)
//  - R12 post-mortem: gemm tile change neutral -> fill/overhead dominate fused.
//  - Gather model (4 rounds of evidence): dur = FETCH / 3.45 TB/s. R13 cuts
//    bytes: one 512-thr block per bucket does the sort ONCE and both column
//    halves (R11 used 2 blocks/bucket -> epk window read twice, sort twice).
//    FETCH 158.5 -> ~146 MB predicted. 4 blocks/CU = 100% wave occupancy.
//    Halves processed sequentially per 8-lane group (interleaving would need
//    ~64 VGPR -> R8 register-recycling trap).

#define D 128
#define NB_SHIFT 6
#define BNODES 64
#define MAXB 2048            // >= nb = 1563
#define CAPB 1408            // mean 1023 + 12 sigma
#define RPT 3                // ceil(CAPB/512)
#define XSTR 136             // LDS row stride (ushorts): 272B = 4-bank shift/row
#define NFILL 256            // fill2 blocks in fused kernel (1 per CU)
#define GROWS 128            // gemm rows per block

using bf16x8 = __attribute__((ext_vector_type(8))) short;
using f32x4  = __attribute__((ext_vector_type(4))) float;

__device__ inline unsigned short f2bf(float f) {
    unsigned u = __float_as_uint(f);
    u += 0x7fffu + ((u >> 16) & 1u);
    return (unsigned short)(u >> 16);
}
__device__ inline float bflo(unsigned w) { return __uint_as_float(w << 16); }
__device__ inline float bfhi(unsigned w) { return __uint_as_float(w & 0xffff0000u); }

// ---------------- wtrans: WT[n][k] = bf16(W[k][n]); also zeroes cursor ----------------
__global__ __launch_bounds__(256) void wtrans(const float* __restrict__ W,
                                              unsigned short* __restrict__ WT,
                                              int* cursor, int nb) {
    const int t = threadIdx.x, b = blockIdx.x;   // 8 blocks
    const int n  = (b << 4) | (t & 15);
    const int k0 = (t >> 4) << 3;
#pragma unroll
    for (int k = k0; k < k0 + 8; ++k)
        WT[n * D + k] = f2bf(W[k * D + n]);
    if (b == 0)
        for (int i = t; i < nb; i += 256) cursor[i] = 0;
}

// ---------------- fused kernel: fill2 path + gemm path ----------------
// LDS union: gemm needs Xl(34.8KB)+Wl(34.8KB)=69.6KB; fill2 needs 16KB.
#define SMEM_BYTES (GROWS * XSTR * 2 + 128 * XSTR * 2)

__device__ void gemm_path(const float* __restrict__ X,
                          const unsigned short* __restrict__ WT,
                          unsigned short* __restrict__ S,
                          int nRows, int blk, char* smem) {
    unsigned short* Xl = (unsigned short*)smem;                       // [128][XSTR]
    unsigned short* Wl = (unsigned short*)(smem + GROWS * XSTR * 2);  // [128][XSTR]

    const int t = threadIdx.x;                 // 0..1023
    const int row0 = blk * GROWS;

    // stage WT (16384 ushort = 2048 uint4), coalesced, 2 iters
    const uint4* WT4 = (const uint4*)WT;
    uint4* Wl4 = (uint4*)Wl;
#pragma unroll
    for (int i = t; i < 2048; i += 1024) {
        int n = i >> 4, kc8 = i & 15;
        Wl4[n * (XSTR / 8) + kc8] = WT4[i];
    }

    // stage X tile fp32 -> bf16 (4096 float4), 4 iters
    const float4* X4 = (const float4*)X;
    ushort4* Xl4 = (ushort4*)Xl;
#pragma unroll
    for (int i = t; i < 4096; i += 1024) {
        int r = i >> 5, c = i & 31;
        int gr = row0 + r;
        float4 v = make_float4(0.f, 0.f, 0.f, 0.f);
        if (gr < nRows) v = X4[(size_t)gr * 32 + c];
        ushort4 p;
        p.x = f2bf(v.x); p.y = f2bf(v.y); p.z = f2bf(v.z); p.w = f2bf(v.w);
        Xl4[r * (XSTR / 4) + c] = p;
    }
    __syncthreads();

    // 16 waves: wave w -> row tile (w&7)*16..+15, nt quad (w>>3)*4..+3
    const int wv = t >> 6, lane = t & 63;
    const int m = lane & 15, quad = lane >> 4;
    const int m0  = (wv & 7) << 4;
    const int nt0 = (wv >> 3) << 2;

    f32x4 acc[4];
    f32x4 z = {0.f, 0.f, 0.f, 0.f};
#pragma unroll
    for (int nt = 0; nt < 4; ++nt) acc[nt] = z;

#pragma unroll
    for (int kc = 0; kc < 4; ++kc) {
        bf16x8 a = *(const bf16x8*)(Xl + (m0 + m) * XSTR + kc * 32 + quad * 8);
#pragma unroll
        for (int nt = 0; nt < 4; ++nt) {
            bf16x8 b = *(const bf16x8*)(Wl + ((nt0 + nt) * 16 + m) * XSTR + kc * 32 + quad * 8);
            acc[nt] = __builtin_amdgcn_mfma_f32_16x16x32_bf16(a, b, acc[nt], 0, 0, 0);
        }
    }

    // D[row = quad*4+r][col = (nt0+nt)*16+m]
#pragma unroll
    for (int nt = 0; nt < 4; ++nt) {
#pragma unroll
        for (int r = 0; r < 4; ++r) {
            int gr = row0 + m0 + quad * 4 + r;
            if (gr < nRows)
                S[(size_t)gr * D + (nt0 + nt) * 16 + m] = f2bf(acc[nt][r]);
        }
    }
}

__device__ void fill2_path(const int* __restrict__ src,
                           const int* __restrict__ dst,
                           const float* __restrict__ vals,
                           int* gcursor, int2* __restrict__ epk,
                           int E, int nb, int blk, char* smem) {
    int* h   = (int*)smem;                  // [MAXB]
    int* cur = (int*)(smem + MAXB * 4);     // [MAXB]
    const int t = threadIdx.x;              // 0..1023
    for (int i = t; i < nb; i += 1024) h[i] = 0;
    __syncthreads();

    int chunk = (E + NFILL - 1) / NFILL;
    chunk = (chunk + 3) & ~3;                     // keep int4 alignment
    const int s0 = min(E, blk * chunk);
    const int s1 = min(E, s0 + chunk);
    const int vend = s0 + ((s1 - s0) & ~3);       // int4 region

    // pass 1: histogram, int4 loads (4 edges/thread/iter)
    int e = s0 + (t << 2);
    for (; e + 4 <= vend; e += 4096) {
        int4 d = *(const int4*)(dst + e);
        atomicAdd(&h[d.x >> NB_SHIFT], 1);
        atomicAdd(&h[d.y >> NB_SHIFT], 1);
        atomicAdd(&h[d.z >> NB_SHIFT], 1);
        atomicAdd(&h[d.w >> NB_SHIFT], 1);
    }
    for (e = vend + t; e < s1; e += 1024) atomicAdd(&h[dst[e] >> NB_SHIFT], 1);
    __syncthreads();

    // reserve per-WG sub-window inside each bucket's fixed window
    for (int i = t; i < nb; i += 1024) {
        int c = h[i];
        cur[i] = c ? (i * CAPB + atomicAdd(&gcursor[i], c)) : 0;
    }
    __syncthreads();

    // pass 2: scatter
    e = s0 + (t << 2);
    for (; e + 4 <= vend; e += 4096) {
        int4   d = *(const int4*)(dst + e);
        int4   s = *(const int4*)(src + e);
        float4 v = *(const float4*)(vals + e);
        int p0 = atomicAdd(&cur[d.x >> NB_SHIFT], 1);
        int p1 = atomicAdd(&cur[d.y >> NB_SHIFT], 1);
        int p2 = atomicAdd(&cur[d.z >> NB_SHIFT], 1);
        int p3 = atomicAdd(&cur[d.w >> NB_SHIFT], 1);
        epk[p0] = make_int2(s.x | ((d.x & (BNODES - 1)) << 20), __float_as_int(v.x));
        epk[p1] = make_int2(s.y | ((d.y & (BNODES - 1)) << 20), __float_as_int(v.y));
        epk[p2] = make_int2(s.z | ((d.z & (BNODES - 1)) << 20), __float_as_int(v.z));
        epk[p3] = make_int2(s.w | ((d.w & (BNODES - 1)) << 20), __float_as_int(v.w));
    }
    for (e = vend + t; e < s1; e += 1024) {
        int d = dst[e];
        int pos = atomicAdd(&cur[d >> NB_SHIFT], 1);
        epk[pos] = make_int2(src[e] | ((d & (BNODES - 1)) << 20), __float_as_int(vals[e]));
    }
}

__global__ __launch_bounds__(1024, 8) void fused_pre(const float* __restrict__ X,
                                                     const unsigned short* __restrict__ WT,
                                                     unsigned short* __restrict__ S,
                                                     int nRows,
                                                     const int* __restrict__ src,
                                                     const int* __restrict__ dst,
                                                     const float* __restrict__ vals,
                                                     int* gcursor, int2* __restrict__ epk,
                                                     int E, int nb) {
    __shared__ char smem[SMEM_BYTES];
    const int bid = blockIdx.x;
    if (bid < NFILL)
        fill2_path(src, dst, vals, gcursor, epk, E, nb, bid, smem);
    else
        gemm_path(X, WT, S, nRows, bid - NFILL, smem);
}

// ---------------- bucket_gather: 512 thr/bucket, shared sort, both halves ----------------
// One block per bucket. Sort phase once (512 threads, RPT=3). Accumulation:
// 64 groups of 8 lanes; group g owns node g, loops half=0,1 sequentially
// (colbase 0 / 8). 12 KB LDS, 4 blocks/CU = 32 waves/CU (100%).
#define ACC8(e, mm) { float v = __int_as_float(e.y);                         \
    a[0] = fmaf(v, bflo(mm.x), a[0]); a[1] = fmaf(v, bfhi(mm.x), a[1]);      \
    a[2] = fmaf(v, bflo(mm.y), a[2]); a[3] = fmaf(v, bfhi(mm.y), a[3]);      \
    a[4] = fmaf(v, bflo(mm.z), a[4]); a[5] = fmaf(v, bfhi(mm.z), a[5]);      \
    a[6] = fmaf(v, bflo(mm.w), a[6]); a[7] = fmaf(v, bfhi(mm.w), a[7]); }

__global__ __launch_bounds__(512, 8) void bucket_gather(const unsigned short* __restrict__ support,
                                                        const int* __restrict__ gcursor,
                                                        const int2* __restrict__ epk,
                                                        float* __restrict__ out, int N) {
    __shared__ int2 se[CAPB];       // 11.3 KB
    __shared__ int  hist[BNODES];
    __shared__ int  rows[BNODES];
    __shared__ int  cur[BNODES];

    const int t   = threadIdx.x;    // 0..511
    const int b   = blockIdx.x;     // bucket
    const int cnt = min(gcursor[b], CAPB);
    const int beg = b * CAPB;

    if (t < BNODES) hist[t] = 0;
    __syncthreads();

    // stage this thread's edges in registers: ONE global epk read total
    int2 r[RPT];
#pragma unroll
    for (int i = 0; i < RPT; ++i) {
        int idx = t + (i << 9);
        if (idx < cnt) r[i] = epk[beg + idx];
    }
#pragma unroll
    for (int i = 0; i < RPT; ++i) {
        int idx = t + (i << 9);
        if (idx < cnt) atomicAdd(&hist[(r[i].x >> 20) & (BNODES - 1)], 1);
    }
    __syncthreads();

    // Hillis-Steele inclusive scan of 64 counters
    if (t < BNODES) rows[t] = hist[t];
    __syncthreads();
#pragma unroll
    for (int off = 1; off < BNODES; off <<= 1) {
        int v = 0;
        if (t < BNODES && t >= off) v = rows[t - off];
        __syncthreads();
        if (t < BNODES && t >= off) rows[t] += v;
        __syncthreads();
    }
    if (t < BNODES) cur[t] = rows[t] - hist[t];
    __syncthreads();

    // scatter registers into sorted LDS order
#pragma unroll
    for (int i = 0; i < RPT; ++i) {
        int idx = t + (i << 9);
        if (idx < cnt) {
            int pos = atomicAdd(&cur[(r[i].x >> 20) & (BNODES - 1)], 1);
            se[pos] = r[i];
        }
    }
    __syncthreads();

    // per-node accumulation: group g (8 lanes) owns node g; halves sequential
    const int g = t >> 3, lane = t & 7;       // 64 groups
    const int node0 = b << NB_SHIFT;
    const uint4* S4 = (const uint4*)support;
    float4* o4 = (float4*)out;

    const int send = rows[g];
    const int sbeg = send - hist[g];
    const int gn   = node0 + g;

    for (int half = 0; half < 2; ++half) {
        const int colbase = half << 3;        // uint4 offset within support row

        float a[8];
#pragma unroll
        for (int k = 0; k < 8; ++k) a[k] = 0.f;

        int j = sbeg;
        for (; j + 4 <= send; j += 4) {       // 4 outstanding 128 B gathers
            int2 e0 = se[j], e1 = se[j + 1], e2 = se[j + 2], e3 = se[j + 3];
            uint4 m0 = S4[(size_t)(e0.x & 0xFFFFF) * 16 + colbase + lane];
            uint4 m1 = S4[(size_t)(e1.x & 0xFFFFF) * 16 + colbase + lane];
            uint4 m2 = S4[(size_t)(e2.x & 0xFFFFF) * 16 + colbase + lane];
            uint4 m3 = S4[(size_t)(e3.x & 0xFFFFF) * 16 + colbase + lane];
            ACC8(e0, m0); ACC8(e1, m1); ACC8(e2, m2); ACC8(e3, m3);
        }
        for (; j < send; ++j) {
            int2 e0 = se[j];
            uint4 m0 = S4[(size_t)(e0.x & 0xFFFFF) * 16 + colbase + lane];
            ACC8(e0, m0);
        }

        if (gn < N) {
            size_t base = (size_t)gn * 32 + (half << 4) + 2 * lane;
            float4 lo = make_float4(fmaxf(a[0], 0.f), fmaxf(a[1], 0.f),
                                    fmaxf(a[2], 0.f), fmaxf(a[3], 0.f));
            float4 hi = make_float4(fmaxf(a[4], 0.f), fmaxf(a[5], 0.f),
                                    fmaxf(a[6], 0.f), fmaxf(a[7], 0.f));
            o4[base]     = lo;
            o4[base + 1] = hi;
        }
    }
}

extern "C" void kernel_launch(void* const* d_in, const int* in_sizes, int n_in,
                              void* d_out, int out_size, void* d_ws, size_t ws_size,
                              hipStream_t stream) {
    const float* X    = (const float*)d_in[0];
    const float* W    = (const float*)d_in[1];
    const float* vals = (const float*)d_in[2];
    const int*   src  = (const int*)d_in[3];
    const int*   dst  = (const int*)d_in[4];
    float*       out  = (float*)d_out;

    const int N  = in_sizes[0] / D;
    const int E  = in_sizes[2];
    const int nb = (N + BNODES - 1) / BNODES;   // 1563

    size_t off = 0;
    auto take = [&](size_t bytes) {
        size_t p = off;
        off = (off + bytes + 255) & ~(size_t)255;
        return p;
    };
    char* ws = (char*)d_ws;
    size_t o_support = take((size_t)N * D * sizeof(unsigned short));
    size_t o_wt      = take((size_t)D * D * sizeof(unsigned short));
    size_t o_cursor  = take((size_t)nb * sizeof(int));
    size_t o_epk     = take(((size_t)nb * CAPB + 1024) * sizeof(int2));
    (void)ws_size;

    unsigned short* support = (unsigned short*)(ws + o_support);
    unsigned short* WT      = (unsigned short*)(ws + o_wt);
    int*  cursor = (int*)(ws + o_cursor);
    int2* epk    = (int2*)(ws + o_epk);

    // 1) WT = bf16(W^T); zero bucket cursors
    wtrans<<<8, 256, 0, stream>>>(W, WT, cursor, nb);

    // 2) fused: fill2 (blocks 0..255) || gemm (blocks 256..256+nbG-1)
    const int nbG = (N + GROWS - 1) / GROWS;    // 782
    fused_pre<<<NFILL + nbG, 1024, 0, stream>>>(X, WT, support, N,
                                                src, dst, vals, cursor, epk, E, nb);

    // 3) per-bucket sort + gather + ReLU (one 512-thr block per bucket)
    bucket_gather<<<nb, 512, 0, stream>>>(support, cursor, epk, out, N);
}

// Round 7
// 196.088 us; speedup vs baseline: 1.0439x; 1.0439x over previous
//
#include <hip/hip_runtime.h>
#include <hip/hip_bf16.h>

// Pipeline (R14): wtrans -> fused(gemm||fill2) -> bucket_gather(R11 col-split)
//  - R13 post-mortem: 512-thr shared-sort gather RAISED L2-miss bytes
//    (166.9 vs 158.5 MB; sequential half-passes doubled temporal footprint,
//    L2 hit rate fell more than the epk dedup saved). dur tracked
//    FETCH/3.45TB/s to 1% again. Gather reverted to R11 exact (61.5us).
//  - R14 fill: SINGLE-PASS. Thread stages its <=8 edges (src/dst/vals int4
//    x2) in regs during histogram; scatter after cursor barrier runs from
//    regs (no dst re-read, no 2nd global latency chain). ~24 extra VGPR,
//    under the 64-VGPR cap for 2x1024thr/CU.

#define D 128
#define NB_SHIFT 6
#define BNODES 64
#define MAXB 2048            // >= nb = 1563
#define CAPB 1408            // mean 1023 + 12 sigma
#define RPT 6                // ceil(CAPB/256)
#define XSTR 136             // LDS row stride (ushorts): 272B = 4-bank shift/row
#define NFILL 256            // fill2 blocks in fused kernel (1 per CU)
#define GROWS 128            // gemm rows per block

using bf16x8 = __attribute__((ext_vector_type(8))) short;
using f32x4  = __attribute__((ext_vector_type(4))) float;

__device__ inline unsigned short f2bf(float f) {
    unsigned u = __float_as_uint(f);
    u += 0x7fffu + ((u >> 16) & 1u);
    return (unsigned short)(u >> 16);
}
__device__ inline float bflo(unsigned w) { return __uint_as_float(w << 16); }
__device__ inline float bfhi(unsigned w) { return __uint_as_float(w & 0xffff0000u); }

// ---------------- wtrans: WT[n][k] = bf16(W[k][n]); also zeroes cursor ----------------
__global__ __launch_bounds__(256) void wtrans(const float* __restrict__ W,
                                              unsigned short* __restrict__ WT,
                                              int* cursor, int nb) {
    const int t = threadIdx.x, b = blockIdx.x;   // 8 blocks
    const int n  = (b << 4) | (t & 15);
    const int k0 = (t >> 4) << 3;
#pragma unroll
    for (int k = k0; k < k0 + 8; ++k)
        WT[n * D + k] = f2bf(W[k * D + n]);
    if (b == 0)
        for (int i = t; i < nb; i += 256) cursor[i] = 0;
}

// ---------------- fused kernel: fill2 path + gemm path ----------------
// LDS union: gemm needs Xl(34.8KB)+Wl(34.8KB)=69.6KB; fill2 needs 16KB.
#define SMEM_BYTES (GROWS * XSTR * 2 + 128 * XSTR * 2)

__device__ void gemm_path(const float* __restrict__ X,
                          const unsigned short* __restrict__ WT,
                          unsigned short* __restrict__ S,
                          int nRows, int blk, char* smem) {
    unsigned short* Xl = (unsigned short*)smem;                       // [128][XSTR]
    unsigned short* Wl = (unsigned short*)(smem + GROWS * XSTR * 2);  // [128][XSTR]

    const int t = threadIdx.x;                 // 0..1023
    const int row0 = blk * GROWS;

    // stage WT (16384 ushort = 2048 uint4), coalesced, 2 iters
    const uint4* WT4 = (const uint4*)WT;
    uint4* Wl4 = (uint4*)Wl;
#pragma unroll
    for (int i = t; i < 2048; i += 1024) {
        int n = i >> 4, kc8 = i & 15;
        Wl4[n * (XSTR / 8) + kc8] = WT4[i];
    }

    // stage X tile fp32 -> bf16 (4096 float4), 4 iters
    const float4* X4 = (const float4*)X;
    ushort4* Xl4 = (ushort4*)Xl;
#pragma unroll
    for (int i = t; i < 4096; i += 1024) {
        int r = i >> 5, c = i & 31;
        int gr = row0 + r;
        float4 v = make_float4(0.f, 0.f, 0.f, 0.f);
        if (gr < nRows) v = X4[(size_t)gr * 32 + c];
        ushort4 p;
        p.x = f2bf(v.x); p.y = f2bf(v.y); p.z = f2bf(v.z); p.w = f2bf(v.w);
        Xl4[r * (XSTR / 4) + c] = p;
    }
    __syncthreads();

    // 16 waves: wave w -> row tile (w&7)*16..+15, nt quad (w>>3)*4..+3
    const int wv = t >> 6, lane = t & 63;
    const int m = lane & 15, quad = lane >> 4;
    const int m0  = (wv & 7) << 4;
    const int nt0 = (wv >> 3) << 2;

    f32x4 acc[4];
    f32x4 z = {0.f, 0.f, 0.f, 0.f};
#pragma unroll
    for (int nt = 0; nt < 4; ++nt) acc[nt] = z;

#pragma unroll
    for (int kc = 0; kc < 4; ++kc) {
        bf16x8 a = *(const bf16x8*)(Xl + (m0 + m) * XSTR + kc * 32 + quad * 8);
#pragma unroll
        for (int nt = 0; nt < 4; ++nt) {
            bf16x8 b = *(const bf16x8*)(Wl + ((nt0 + nt) * 16 + m) * XSTR + kc * 32 + quad * 8);
            acc[nt] = __builtin_amdgcn_mfma_f32_16x16x32_bf16(a, b, acc[nt], 0, 0, 0);
        }
    }

    // D[row = quad*4+r][col = (nt0+nt)*16+m]
#pragma unroll
    for (int nt = 0; nt < 4; ++nt) {
#pragma unroll
        for (int r = 0; r < 4; ++r) {
            int gr = row0 + m0 + quad * 4 + r;
            if (gr < nRows)
                S[(size_t)gr * D + (nt0 + nt) * 16 + m] = f2bf(acc[nt][r]);
        }
    }
}

__device__ void fill2_path(const int* __restrict__ src,
                           const int* __restrict__ dst,
                           const float* __restrict__ vals,
                           int* gcursor, int2* __restrict__ epk,
                           int E, int nb, int blk, char* smem) {
    int* h   = (int*)smem;                  // [MAXB]
    int* cur = (int*)(smem + MAXB * 4);     // [MAXB]
    const int t = threadIdx.x;              // 0..1023
    for (int i = t; i < nb; i += 1024) h[i] = 0;
    __syncthreads();

    int chunk = (E + NFILL - 1) / NFILL;
    chunk = (chunk + 3) & ~3;                     // keep int4 alignment
    const int s0 = min(E, blk * chunk);
    const int s1 = min(E, s0 + chunk);
    const int vend = s0 + ((s1 - s0) & ~3);       // int4 region

    // single pass: stage this thread's edges (<=2 int4 groups) in regs
    // while building the histogram
    const int e0 = s0 + (t << 2);
    const int e1 = e0 + 4096;
    int4 rs0, rd0, rs1, rd1;
    float4 rv0, rv1;
    const bool has0 = (e0 + 4 <= vend);
    const bool has1 = (e1 + 4 <= vend);
    if (has0) {
        rd0 = *(const int4*)(dst + e0);
        rs0 = *(const int4*)(src + e0);
        rv0 = *(const float4*)(vals + e0);
        atomicAdd(&h[rd0.x >> NB_SHIFT], 1);
        atomicAdd(&h[rd0.y >> NB_SHIFT], 1);
        atomicAdd(&h[rd0.z >> NB_SHIFT], 1);
        atomicAdd(&h[rd0.w >> NB_SHIFT], 1);
    }
    if (has1) {
        rd1 = *(const int4*)(dst + e1);
        rs1 = *(const int4*)(src + e1);
        rv1 = *(const float4*)(vals + e1);
        atomicAdd(&h[rd1.x >> NB_SHIFT], 1);
        atomicAdd(&h[rd1.y >> NB_SHIFT], 1);
        atomicAdd(&h[rd1.z >> NB_SHIFT], 1);
        atomicAdd(&h[rd1.w >> NB_SHIFT], 1);
    }
    // scalar tail (<4 edges per block)
    for (int e = vend + t; e < s1; e += 1024)
        atomicAdd(&h[dst[e] >> NB_SHIFT], 1);
    __syncthreads();

    // reserve per-WG sub-window inside each bucket's fixed window
    for (int i = t; i < nb; i += 1024) {
        int c = h[i];
        cur[i] = c ? (i * CAPB + atomicAdd(&gcursor[i], c)) : 0;
    }
    __syncthreads();

    // scatter from registers (no global re-read)
    if (has0) {
        int p0 = atomicAdd(&cur[rd0.x >> NB_SHIFT], 1);
        int p1 = atomicAdd(&cur[rd0.y >> NB_SHIFT], 1);
        int p2 = atomicAdd(&cur[rd0.z >> NB_SHIFT], 1);
        int p3 = atomicAdd(&cur[rd0.w >> NB_SHIFT], 1);
        epk[p0] = make_int2(rs0.x | ((rd0.x & (BNODES - 1)) << 20), __float_as_int(rv0.x));
        epk[p1] = make_int2(rs0.y | ((rd0.y & (BNODES - 1)) << 20), __float_as_int(rv0.y));
        epk[p2] = make_int2(rs0.z | ((rd0.z & (BNODES - 1)) << 20), __float_as_int(rv0.z));
        epk[p3] = make_int2(rs0.w | ((rd0.w & (BNODES - 1)) << 20), __float_as_int(rv0.w));
    }
    if (has1) {
        int p0 = atomicAdd(&cur[rd1.x >> NB_SHIFT], 1);
        int p1 = atomicAdd(&cur[rd1.y >> NB_SHIFT], 1);
        int p2 = atomicAdd(&cur[rd1.z >> NB_SHIFT], 1);
        int p3 = atomicAdd(&cur[rd1.w >> NB_SHIFT], 1);
        epk[p0] = make_int2(rs1.x | ((rd1.x & (BNODES - 1)) << 20), __float_as_int(rv1.x));
        epk[p1] = make_int2(rs1.y | ((rd1.y & (BNODES - 1)) << 20), __float_as_int(rv1.y));
        epk[p2] = make_int2(rs1.z | ((rd1.z & (BNODES - 1)) << 20), __float_as_int(rv1.z));
        epk[p3] = make_int2(rs1.w | ((rd1.w & (BNODES - 1)) << 20), __float_as_int(rv1.w));
    }
    for (int e = vend + t; e < s1; e += 1024) {
        int d = dst[e];
        int pos = atomicAdd(&cur[d >> NB_SHIFT], 1);
        epk[pos] = make_int2(src[e] | ((d & (BNODES - 1)) << 20), __float_as_int(vals[e]));
    }
}

__global__ __launch_bounds__(1024, 8) void fused_pre(const float* __restrict__ X,
                                                     const unsigned short* __restrict__ WT,
                                                     unsigned short* __restrict__ S,
                                                     int nRows,
                                                     const int* __restrict__ src,
                                                     const int* __restrict__ dst,
                                                     const float* __restrict__ vals,
                                                     int* gcursor, int2* __restrict__ epk,
                                                     int E, int nb) {
    __shared__ char smem[SMEM_BYTES];
    const int bid = blockIdx.x;
    if (bid < NFILL)
        fill2_path(src, dst, vals, gcursor, epk, E, nb, bid, smem);
    else
        gemm_path(X, WT, S, nRows, bid - NFILL, smem);
}

// ---------------- bucket_gather: column-split, 2 blocks per bucket (R11 exact) ----------------
// Block 2b+h: bucket b, output cols h*64..h*64+63. 3126 blocks of 256 thr;
// 12.3 KB LDS -> 8 blocks/CU; per-node group = 8 lanes x 16B (one 128B line).
#define ACC8(e, mm) { float v = __int_as_float(e.y);                         \
    a[0] = fmaf(v, bflo(mm.x), a[0]); a[1] = fmaf(v, bfhi(mm.x), a[1]);      \
    a[2] = fmaf(v, bflo(mm.y), a[2]); a[3] = fmaf(v, bfhi(mm.y), a[3]);      \
    a[4] = fmaf(v, bflo(mm.z), a[4]); a[5] = fmaf(v, bfhi(mm.z), a[5]);      \
    a[6] = fmaf(v, bflo(mm.w), a[6]); a[7] = fmaf(v, bfhi(mm.w), a[7]); }

__global__ __launch_bounds__(256, 8) void bucket_gather(const unsigned short* __restrict__ support,
                                                        const int* __restrict__ gcursor,
                                                        const int2* __restrict__ epk,
                                                        float* __restrict__ out, int N) {
    __shared__ int2 se[CAPB];       // 11.3 KB
    __shared__ int  hist[BNODES];
    __shared__ int  rows[BNODES];
    __shared__ int  cur[BNODES];

    const int t    = threadIdx.x;
    const int b    = blockIdx.x >> 1;     // bucket
    const int half = blockIdx.x & 1;      // column half (0: cols 0-63, 1: 64-127)
    const int cnt  = min(gcursor[b], CAPB);
    const int beg  = b * CAPB;

    if (t < BNODES) hist[t] = 0;
    __syncthreads();

    // stage this thread's edges in registers: ONE global epk read total
    int2 r[RPT];
#pragma unroll
    for (int i = 0; i < RPT; ++i) {
        int idx = t + (i << 8);
        if (idx < cnt) r[i] = epk[beg + idx];
    }
#pragma unroll
    for (int i = 0; i < RPT; ++i) {
        int idx = t + (i << 8);
        if (idx < cnt) atomicAdd(&hist[(r[i].x >> 20) & (BNODES - 1)], 1);
    }
    __syncthreads();

    // Hillis-Steele inclusive scan of 64 counters
    if (t < BNODES) rows[t] = hist[t];
    __syncthreads();
#pragma unroll
    for (int off = 1; off < BNODES; off <<= 1) {
        int v = 0;
        if (t < BNODES && t >= off) v = rows[t - off];
        __syncthreads();
        if (t < BNODES && t >= off) rows[t] += v;
        __syncthreads();
    }
    if (t < BNODES) cur[t] = rows[t] - hist[t];
    __syncthreads();

    // scatter registers into sorted LDS order
#pragma unroll
    for (int i = 0; i < RPT; ++i) {
        int idx = t + (i << 8);
        if (idx < cnt) {
            int pos = atomicAdd(&cur[(r[i].x >> 20) & (BNODES - 1)], 1);
            se[pos] = r[i];
        }
    }
    __syncthreads();

    // per-node accumulation: group g (8 lanes) handles nodes g, g+32
    const int g = t >> 3, lane = t & 7;
    const int node0 = b << NB_SHIFT;
    const int colbase = half << 3;               // uint4 offset within support row
    const uint4* S4 = (const uint4*)support;
    float4* o4 = (float4*)out;

#pragma unroll
    for (int nn = g; nn < BNODES; nn += 32) {
        const int send = rows[nn];
        const int sbeg = send - hist[nn];

        float a[8];
#pragma unroll
        for (int k = 0; k < 8; ++k) a[k] = 0.f;

        int j = sbeg;
        for (; j + 4 <= send; j += 4) {          // 4 outstanding 128 B gathers
            int2 e0 = se[j], e1 = se[j + 1], e2 = se[j + 2], e3 = se[j + 3];
            uint4 m0 = S4[(size_t)(e0.x & 0xFFFFF) * 16 + colbase + lane];
            uint4 m1 = S4[(size_t)(e1.x & 0xFFFFF) * 16 + colbase + lane];
            uint4 m2 = S4[(size_t)(e2.x & 0xFFFFF) * 16 + colbase + lane];
            uint4 m3 = S4[(size_t)(e3.x & 0xFFFFF) * 16 + colbase + lane];
            ACC8(e0, m0); ACC8(e1, m1); ACC8(e2, m2); ACC8(e3, m3);
        }
        for (; j < send; ++j) {
            int2 e0 = se[j];
            uint4 m0 = S4[(size_t)(e0.x & 0xFFFFF) * 16 + colbase + lane];
            ACC8(e0, m0);
        }

        const int gn = node0 + nn;
        if (gn < N) {
            size_t base = (size_t)gn * 32 + (half << 4) + 2 * lane;
            float4 lo = make_float4(fmaxf(a[0], 0.f), fmaxf(a[1], 0.f),
                                    fmaxf(a[2], 0.f), fmaxf(a[3], 0.f));
            float4 hi = make_float4(fmaxf(a[4], 0.f), fmaxf(a[5], 0.f),
                                    fmaxf(a[6], 0.f), fmaxf(a[7], 0.f));
            o4[base]     = lo;
            o4[base + 1] = hi;
        }
    }
}

extern "C" void kernel_launch(void* const* d_in, const int* in_sizes, int n_in,
                              void* d_out, int out_size, void* d_ws, size_t ws_size,
                              hipStream_t stream) {
    const float* X    = (const float*)d_in[0];
    const float* W    = (const float*)d_in[1];
    const float* vals = (const float*)d_in[2];
    const int*   src  = (const int*)d_in[3];
    const int*   dst  = (const int*)d_in[4];
    float*       out  = (float*)d_out;

    const int N  = in_sizes[0] / D;
    const int E  = in_sizes[2];
    const int nb = (N + BNODES - 1) / BNODES;   // 1563

    size_t off = 0;
    auto take = [&](size_t bytes) {
        size_t p = off;
        off = (off + bytes + 255) & ~(size_t)255;
        return p;
    };
    char* ws = (char*)d_ws;
    size_t o_support = take((size_t)N * D * sizeof(unsigned short));
    size_t o_wt      = take((size_t)D * D * sizeof(unsigned short));
    size_t o_cursor  = take((size_t)nb * sizeof(int));
    size_t o_epk     = take(((size_t)nb * CAPB + 1024) * sizeof(int2));
    (void)ws_size;

    unsigned short* support = (unsigned short*)(ws + o_support);
    unsigned short* WT      = (unsigned short*)(ws + o_wt);
    int*  cursor = (int*)(ws + o_cursor);
    int2* epk    = (int2*)(ws + o_epk);

    // 1) WT = bf16(W^T); zero bucket cursors
    wtrans<<<8, 256, 0, stream>>>(W, WT, cursor, nb);

    // 2) fused: fill2 (blocks 0..255) || gemm (blocks 256..256+nbG-1)
    const int nbG = (N + GROWS - 1) / GROWS;    // 782
    fused_pre<<<NFILL + nbG, 1024, 0, stream>>>(X, WT, support, N,
                                                src, dst, vals, cursor, epk, E, nb);

    // 3) per-bucket sort + gather + ReLU (2 blocks per bucket, column-split)
    bucket_gather<<<2 * nb, 256, 0, stream>>>(support, cursor, epk, out, N);
}

// Round 8
// 195.964 us; speedup vs baseline: 1.0445x; 1.0006x over previous
//
#include <hip/hip_runtime.h>
#include <hip/hip_bf16.h>

// Pipeline (R15): wtrans -> fused(gemm||fill2) -> bucket_gather(XCD-partitioned halves)
//  - R14: single-pass fill confirmed (+1.1us), best total 196.1.
//  - R15: gather block mapping partitions column halves across XCDs
//    (bid%8 round-robin assumption: (bid&7)<4 -> half 0, >=4 -> half 1).
//    Each XCD's L2 gather footprint 25.6 -> 12.8 MB (per half, one 128B
//    line per support row, ~16 requests/line dedup potential) -> higher
//    L2 hit -> lower FETCH. Pre-registered: FETCH unchanged => mapping
//    wrong / L2 not the limiter => gather at floor.

#define D 128
#define NB_SHIFT 6
#define BNODES 64
#define MAXB 2048            // >= nb = 1563
#define CAPB 1408            // mean 1023 + 12 sigma
#define RPT 6                // ceil(CAPB/256)
#define XSTR 136             // LDS row stride (ushorts): 272B = 4-bank shift/row
#define NFILL 256            // fill2 blocks in fused kernel (1 per CU)
#define GROWS 128            // gemm rows per block

using bf16x8 = __attribute__((ext_vector_type(8))) short;
using f32x4  = __attribute__((ext_vector_type(4))) float;

__device__ inline unsigned short f2bf(float f) {
    unsigned u = __float_as_uint(f);
    u += 0x7fffu + ((u >> 16) & 1u);
    return (unsigned short)(u >> 16);
}
__device__ inline float bflo(unsigned w) { return __uint_as_float(w << 16); }
__device__ inline float bfhi(unsigned w) { return __uint_as_float(w & 0xffff0000u); }

// ---------------- wtrans: WT[n][k] = bf16(W[k][n]); also zeroes cursor ----------------
__global__ __launch_bounds__(256) void wtrans(const float* __restrict__ W,
                                              unsigned short* __restrict__ WT,
                                              int* cursor, int nb) {
    const int t = threadIdx.x, b = blockIdx.x;   // 8 blocks
    const int n  = (b << 4) | (t & 15);
    const int k0 = (t >> 4) << 3;
#pragma unroll
    for (int k = k0; k < k0 + 8; ++k)
        WT[n * D + k] = f2bf(W[k * D + n]);
    if (b == 0)
        for (int i = t; i < nb; i += 256) cursor[i] = 0;
}

// ---------------- fused kernel: fill2 path + gemm path ----------------
// LDS union: gemm needs Xl(34.8KB)+Wl(34.8KB)=69.6KB; fill2 needs 16KB.
#define SMEM_BYTES (GROWS * XSTR * 2 + 128 * XSTR * 2)

__device__ void gemm_path(const float* __restrict__ X,
                          const unsigned short* __restrict__ WT,
                          unsigned short* __restrict__ S,
                          int nRows, int blk, char* smem) {
    unsigned short* Xl = (unsigned short*)smem;                       // [128][XSTR]
    unsigned short* Wl = (unsigned short*)(smem + GROWS * XSTR * 2);  // [128][XSTR]

    const int t = threadIdx.x;                 // 0..1023
    const int row0 = blk * GROWS;

    // stage WT (16384 ushort = 2048 uint4), coalesced, 2 iters
    const uint4* WT4 = (const uint4*)WT;
    uint4* Wl4 = (uint4*)Wl;
#pragma unroll
    for (int i = t; i < 2048; i += 1024) {
        int n = i >> 4, kc8 = i & 15;
        Wl4[n * (XSTR / 8) + kc8] = WT4[i];
    }

    // stage X tile fp32 -> bf16 (4096 float4), 4 iters
    const float4* X4 = (const float4*)X;
    ushort4* Xl4 = (ushort4*)Xl;
#pragma unroll
    for (int i = t; i < 4096; i += 1024) {
        int r = i >> 5, c = i & 31;
        int gr = row0 + r;
        float4 v = make_float4(0.f, 0.f, 0.f, 0.f);
        if (gr < nRows) v = X4[(size_t)gr * 32 + c];
        ushort4 p;
        p.x = f2bf(v.x); p.y = f2bf(v.y); p.z = f2bf(v.z); p.w = f2bf(v.w);
        Xl4[r * (XSTR / 4) + c] = p;
    }
    __syncthreads();

    // 16 waves: wave w -> row tile (w&7)*16..+15, nt quad (w>>3)*4..+3
    const int wv = t >> 6, lane = t & 63;
    const int m = lane & 15, quad = lane >> 4;
    const int m0  = (wv & 7) << 4;
    const int nt0 = (wv >> 3) << 2;

    f32x4 acc[4];
    f32x4 z = {0.f, 0.f, 0.f, 0.f};
#pragma unroll
    for (int nt = 0; nt < 4; ++nt) acc[nt] = z;

#pragma unroll
    for (int kc = 0; kc < 4; ++kc) {
        bf16x8 a = *(const bf16x8*)(Xl + (m0 + m) * XSTR + kc * 32 + quad * 8);
#pragma unroll
        for (int nt = 0; nt < 4; ++nt) {
            bf16x8 b = *(const bf16x8*)(Wl + ((nt0 + nt) * 16 + m) * XSTR + kc * 32 + quad * 8);
            acc[nt] = __builtin_amdgcn_mfma_f32_16x16x32_bf16(a, b, acc[nt], 0, 0, 0);
        }
    }

    // D[row = quad*4+r][col = (nt0+nt)*16+m]
#pragma unroll
    for (int nt = 0; nt < 4; ++nt) {
#pragma unroll
        for (int r = 0; r < 4; ++r) {
            int gr = row0 + m0 + quad * 4 + r;
            if (gr < nRows)
                S[(size_t)gr * D + (nt0 + nt) * 16 + m] = f2bf(acc[nt][r]);
        }
    }
}

__device__ void fill2_path(const int* __restrict__ src,
                           const int* __restrict__ dst,
                           const float* __restrict__ vals,
                           int* gcursor, int2* __restrict__ epk,
                           int E, int nb, int blk, char* smem) {
    int* h   = (int*)smem;                  // [MAXB]
    int* cur = (int*)(smem + MAXB * 4);     // [MAXB]
    const int t = threadIdx.x;              // 0..1023
    for (int i = t; i < nb; i += 1024) h[i] = 0;
    __syncthreads();

    int chunk = (E + NFILL - 1) / NFILL;
    chunk = (chunk + 3) & ~3;                     // keep int4 alignment
    const int s0 = min(E, blk * chunk);
    const int s1 = min(E, s0 + chunk);
    const int vend = s0 + ((s1 - s0) & ~3);       // int4 region

    // single pass: stage this thread's edges (<=2 int4 groups) in regs
    // while building the histogram
    const int e0 = s0 + (t << 2);
    const int e1 = e0 + 4096;
    int4 rs0, rd0, rs1, rd1;
    float4 rv0, rv1;
    const bool has0 = (e0 + 4 <= vend);
    const bool has1 = (e1 + 4 <= vend);
    if (has0) {
        rd0 = *(const int4*)(dst + e0);
        rs0 = *(const int4*)(src + e0);
        rv0 = *(const float4*)(vals + e0);
        atomicAdd(&h[rd0.x >> NB_SHIFT], 1);
        atomicAdd(&h[rd0.y >> NB_SHIFT], 1);
        atomicAdd(&h[rd0.z >> NB_SHIFT], 1);
        atomicAdd(&h[rd0.w >> NB_SHIFT], 1);
    }
    if (has1) {
        rd1 = *(const int4*)(dst + e1);
        rs1 = *(const int4*)(src + e1);
        rv1 = *(const float4*)(vals + e1);
        atomicAdd(&h[rd1.x >> NB_SHIFT], 1);
        atomicAdd(&h[rd1.y >> NB_SHIFT], 1);
        atomicAdd(&h[rd1.z >> NB_SHIFT], 1);
        atomicAdd(&h[rd1.w >> NB_SHIFT], 1);
    }
    // scalar tail (<4 edges per block)
    for (int e = vend + t; e < s1; e += 1024)
        atomicAdd(&h[dst[e] >> NB_SHIFT], 1);
    __syncthreads();

    // reserve per-WG sub-window inside each bucket's fixed window
    for (int i = t; i < nb; i += 1024) {
        int c = h[i];
        cur[i] = c ? (i * CAPB + atomicAdd(&gcursor[i], c)) : 0;
    }
    __syncthreads();

    // scatter from registers (no global re-read)
    if (has0) {
        int p0 = atomicAdd(&cur[rd0.x >> NB_SHIFT], 1);
        int p1 = atomicAdd(&cur[rd0.y >> NB_SHIFT], 1);
        int p2 = atomicAdd(&cur[rd0.z >> NB_SHIFT], 1);
        int p3 = atomicAdd(&cur[rd0.w >> NB_SHIFT], 1);
        epk[p0] = make_int2(rs0.x | ((rd0.x & (BNODES - 1)) << 20), __float_as_int(rv0.x));
        epk[p1] = make_int2(rs0.y | ((rd0.y & (BNODES - 1)) << 20), __float_as_int(rv0.y));
        epk[p2] = make_int2(rs0.z | ((rd0.z & (BNODES - 1)) << 20), __float_as_int(rv0.z));
        epk[p3] = make_int2(rs0.w | ((rd0.w & (BNODES - 1)) << 20), __float_as_int(rv0.w));
    }
    if (has1) {
        int p0 = atomicAdd(&cur[rd1.x >> NB_SHIFT], 1);
        int p1 = atomicAdd(&cur[rd1.y >> NB_SHIFT], 1);
        int p2 = atomicAdd(&cur[rd1.z >> NB_SHIFT], 1);
        int p3 = atomicAdd(&cur[rd1.w >> NB_SHIFT], 1);
        epk[p0] = make_int2(rs1.x | ((rd1.x & (BNODES - 1)) << 20), __float_as_int(rv1.x));
        epk[p1] = make_int2(rs1.y | ((rd1.y & (BNODES - 1)) << 20), __float_as_int(rv1.y));
        epk[p2] = make_int2(rs1.z | ((rd1.z & (BNODES - 1)) << 20), __float_as_int(rv1.z));
        epk[p3] = make_int2(rs1.w | ((rd1.w & (BNODES - 1)) << 20), __float_as_int(rv1.w));
    }
    for (int e = vend + t; e < s1; e += 1024) {
        int d = dst[e];
        int pos = atomicAdd(&cur[d >> NB_SHIFT], 1);
        epk[pos] = make_int2(src[e] | ((d & (BNODES - 1)) << 20), __float_as_int(vals[e]));
    }
}

__global__ __launch_bounds__(1024, 8) void fused_pre(const float* __restrict__ X,
                                                     const unsigned short* __restrict__ WT,
                                                     unsigned short* __restrict__ S,
                                                     int nRows,
                                                     const int* __restrict__ src,
                                                     const int* __restrict__ dst,
                                                     const float* __restrict__ vals,
                                                     int* gcursor, int2* __restrict__ epk,
                                                     int E, int nb) {
    __shared__ char smem[SMEM_BYTES];
    const int bid = blockIdx.x;
    if (bid < NFILL)
        fill2_path(src, dst, vals, gcursor, epk, E, nb, bid, smem);
    else
        gemm_path(X, WT, S, nRows, bid - NFILL, smem);
}

// ---------------- bucket_gather: col-split, halves partitioned across XCDs ----------------
// bid%8 -> XCD (round-robin heuristic). (bid&7)<4: half 0, buckets grp*4+q;
// (bid&7)>=4: half 1. Each XCD's L2 support footprint 25.6 -> 12.8 MB.
// Inner structure identical to R11/R14 gather (61us known-good).
#define ACC8(e, mm) { float v = __int_as_float(e.y);                         \
    a[0] = fmaf(v, bflo(mm.x), a[0]); a[1] = fmaf(v, bfhi(mm.x), a[1]);      \
    a[2] = fmaf(v, bflo(mm.y), a[2]); a[3] = fmaf(v, bfhi(mm.y), a[3]);      \
    a[4] = fmaf(v, bflo(mm.z), a[4]); a[5] = fmaf(v, bfhi(mm.z), a[5]);      \
    a[6] = fmaf(v, bflo(mm.w), a[6]); a[7] = fmaf(v, bfhi(mm.w), a[7]); }

__global__ __launch_bounds__(256, 8) void bucket_gather(const unsigned short* __restrict__ support,
                                                        const int* __restrict__ gcursor,
                                                        const int2* __restrict__ epk,
                                                        float* __restrict__ out, int N, int nb) {
    __shared__ int2 se[CAPB];       // 11.3 KB
    __shared__ int  hist[BNODES];
    __shared__ int  rows[BNODES];
    __shared__ int  cur[BNODES];

    const int t     = threadIdx.x;
    const int x8    = blockIdx.x & 7;          // XCD slot (round-robin heuristic)
    const int half  = x8 >> 2;                 // XCDs 0-3: half 0; 4-7: half 1
    const int b     = (blockIdx.x >> 3) * 4 + (x8 & 3);   // bucket
    if (b >= nb) return;
    const int cnt  = min(gcursor[b], CAPB);
    const int beg  = b * CAPB;

    if (t < BNODES) hist[t] = 0;
    __syncthreads();

    // stage this thread's edges in registers: ONE global epk read total
    int2 r[RPT];
#pragma unroll
    for (int i = 0; i < RPT; ++i) {
        int idx = t + (i << 8);
        if (idx < cnt) r[i] = epk[beg + idx];
    }
#pragma unroll
    for (int i = 0; i < RPT; ++i) {
        int idx = t + (i << 8);
        if (idx < cnt) atomicAdd(&hist[(r[i].x >> 20) & (BNODES - 1)], 1);
    }
    __syncthreads();

    // Hillis-Steele inclusive scan of 64 counters
    if (t < BNODES) rows[t] = hist[t];
    __syncthreads();
#pragma unroll
    for (int off = 1; off < BNODES; off <<= 1) {
        int v = 0;
        if (t < BNODES && t >= off) v = rows[t - off];
        __syncthreads();
        if (t < BNODES && t >= off) rows[t] += v;
        __syncthreads();
    }
    if (t < BNODES) cur[t] = rows[t] - hist[t];
    __syncthreads();

    // scatter registers into sorted LDS order
#pragma unroll
    for (int i = 0; i < RPT; ++i) {
        int idx = t + (i << 8);
        if (idx < cnt) {
            int pos = atomicAdd(&cur[(r[i].x >> 20) & (BNODES - 1)], 1);
            se[pos] = r[i];
        }
    }
    __syncthreads();

    // per-node accumulation: group g (8 lanes) handles nodes g, g+32
    const int g = t >> 3, lane = t & 7;
    const int node0 = b << NB_SHIFT;
    const int colbase = half << 3;               // uint4 offset within support row
    const uint4* S4 = (const uint4*)support;
    float4* o4 = (float4*)out;

#pragma unroll
    for (int nn = g; nn < BNODES; nn += 32) {
        const int send = rows[nn];
        const int sbeg = send - hist[nn];

        float a[8];
#pragma unroll
        for (int k = 0; k < 8; ++k) a[k] = 0.f;

        int j = sbeg;
        for (; j + 4 <= send; j += 4) {          // 4 outstanding 128 B gathers
            int2 e0 = se[j], e1 = se[j + 1], e2 = se[j + 2], e3 = se[j + 3];
            uint4 m0 = S4[(size_t)(e0.x & 0xFFFFF) * 16 + colbase + lane];
            uint4 m1 = S4[(size_t)(e1.x & 0xFFFFF) * 16 + colbase + lane];
            uint4 m2 = S4[(size_t)(e2.x & 0xFFFFF) * 16 + colbase + lane];
            uint4 m3 = S4[(size_t)(e3.x & 0xFFFFF) * 16 + colbase + lane];
            ACC8(e0, m0); ACC8(e1, m1); ACC8(e2, m2); ACC8(e3, m3);
        }
        for (; j < send; ++j) {
            int2 e0 = se[j];
            uint4 m0 = S4[(size_t)(e0.x & 0xFFFFF) * 16 + colbase + lane];
            ACC8(e0, m0);
        }

        const int gn = node0 + nn;
        if (gn < N) {
            size_t base = (size_t)gn * 32 + (half << 4) + 2 * lane;
            float4 lo = make_float4(fmaxf(a[0], 0.f), fmaxf(a[1], 0.f),
                                    fmaxf(a[2], 0.f), fmaxf(a[3], 0.f));
            float4 hi = make_float4(fmaxf(a[4], 0.f), fmaxf(a[5], 0.f),
                                    fmaxf(a[6], 0.f), fmaxf(a[7], 0.f));
            o4[base]     = lo;
            o4[base + 1] = hi;
        }
    }
}

extern "C" void kernel_launch(void* const* d_in, const int* in_sizes, int n_in,
                              void* d_out, int out_size, void* d_ws, size_t ws_size,
                              hipStream_t stream) {
    const float* X    = (const float*)d_in[0];
    const float* W    = (const float*)d_in[1];
    const float* vals = (const float*)d_in[2];
    const int*   src  = (const int*)d_in[3];
    const int*   dst  = (const int*)d_in[4];
    float*       out  = (float*)d_out;

    const int N  = in_sizes[0] / D;
    const int E  = in_sizes[2];
    const int nb = (N + BNODES - 1) / BNODES;   // 1563

    size_t off = 0;
    auto take = [&](size_t bytes) {
        size_t p = off;
        off = (off + bytes + 255) & ~(size_t)255;
        return p;
    };
    char* ws = (char*)d_ws;
    size_t o_support = take((size_t)N * D * sizeof(unsigned short));
    size_t o_wt      = take((size_t)D * D * sizeof(unsigned short));
    size_t o_cursor  = take((size_t)nb * sizeof(int));
    size_t o_epk     = take(((size_t)nb * CAPB + 1024) * sizeof(int2));
    (void)ws_size;

    unsigned short* support = (unsigned short*)(ws + o_support);
    unsigned short* WT      = (unsigned short*)(ws + o_wt);
    int*  cursor = (int*)(ws + o_cursor);
    int2* epk    = (int2*)(ws + o_epk);

    // 1) WT = bf16(W^T); zero bucket cursors
    wtrans<<<8, 256, 0, stream>>>(W, WT, cursor, nb);

    // 2) fused: fill2 (blocks 0..255) || gemm (blocks 256..256+nbG-1)
    const int nbG = (N + GROWS - 1) / GROWS;    // 782
    fused_pre<<<NFILL + nbG, 1024, 0, stream>>>(X, WT, support, N,
                                                src, dst, vals, cursor, epk, E, nb);

    // 3) gather: halves partitioned across XCDs; grid = ceil(nb/4)*8
    const int gblocks = ((nb + 3) / 4) * 8;
    bucket_gather<<<gblocks, 256, 0, stream>>>(support, cursor, epk, out, N, nb);
}

// Round 9
// 192.238 us; speedup vs baseline: 1.0648x; 1.0194x over previous
//
#include <hip/hip_runtime.h>
#include <hip/hip_bf16.h>

// Pipeline (R16): wtrans -> fused(gemm||fill2) -> bucket_gather(int8 support)
//  - R15 post-mortem: XCD half-partition null on FETCH -> bf16 gather bytes
//    at structural floor (158.5MB @ pinned 3.45TB/s, 6 rounds of model).
//  - R16: support stored INT8 with per-row fp32 scale (computed in gemm
//    epilogue via LDS atomicMax row-abs-max). Row = one 128B line shared by
//    both column halves: footprint 25.6->12.8MB, reuse/line 16->32 -> L2
//    hit jump. Gather: uint2 loads + cvt-ubyte dequant, svs trick
//    (a_k = sum vs*q - 128*sum vs). Bucket halves co-located on one XCD
//    slot (bid=(b>>3)*16+(b&7)+(h<<3)) so shared lines aren't double-fetched
//    across XCDs. Quant err ~rowmax/254 -> absmax predicted ~0.1-0.15.

#define D 128
#define NB_SHIFT 6
#define BNODES 64
#define MAXB 2048            // >= nb = 1563
#define CAPB 1408            // mean 1023 + 12 sigma
#define RPT 6                // ceil(CAPB/256)
#define XSTR 136             // LDS row stride (ushorts): 272B = 4-bank shift/row
#define NFILL 256            // fill2 blocks in fused kernel (1 per CU)
#define GROWS 128            // gemm rows per block

using bf16x8 = __attribute__((ext_vector_type(8))) short;
using f32x4  = __attribute__((ext_vector_type(4))) float;

__device__ inline unsigned short f2bf(float f) {
    unsigned u = __float_as_uint(f);
    u += 0x7fffu + ((u >> 16) & 1u);
    return (unsigned short)(u >> 16);
}

// ---------------- wtrans: WT[n][k] = bf16(W[k][n]); also zeroes cursor ----------------
__global__ __launch_bounds__(256) void wtrans(const float* __restrict__ W,
                                              unsigned short* __restrict__ WT,
                                              int* cursor, int nb) {
    const int t = threadIdx.x, b = blockIdx.x;   // 8 blocks
    const int n  = (b << 4) | (t & 15);
    const int k0 = (t >> 4) << 3;
#pragma unroll
    for (int k = k0; k < k0 + 8; ++k)
        WT[n * D + k] = f2bf(W[k * D + n]);
    if (b == 0)
        for (int i = t; i < nb; i += 256) cursor[i] = 0;
}

// ---------------- fused kernel: fill2 path + gemm path ----------------
// LDS union: gemm needs Xl(34.8KB)+Wl(34.8KB)+rowAmax(512B); fill2 needs 16KB.
#define SMEM_BYTES (GROWS * XSTR * 2 + 128 * XSTR * 2 + GROWS * 4)

__device__ void gemm_path(const float* __restrict__ X,
                          const unsigned short* __restrict__ WT,
                          unsigned char* __restrict__ S8,
                          float* __restrict__ scaleArr,
                          int nRows, int blk, char* smem) {
    unsigned short* Xl = (unsigned short*)smem;                       // [128][XSTR]
    unsigned short* Wl = (unsigned short*)(smem + GROWS * XSTR * 2);  // [128][XSTR]
    int* rowAmaxI = (int*)(smem + GROWS * XSTR * 2 + 128 * XSTR * 2); // [128]

    const int t = threadIdx.x;                 // 0..1023
    const int row0 = blk * GROWS;

    if (t < GROWS) rowAmaxI[t] = 0;

    // stage WT (16384 ushort = 2048 uint4), coalesced, 2 iters
    const uint4* WT4 = (const uint4*)WT;
    uint4* Wl4 = (uint4*)Wl;
#pragma unroll
    for (int i = t; i < 2048; i += 1024) {
        int n = i >> 4, kc8 = i & 15;
        Wl4[n * (XSTR / 8) + kc8] = WT4[i];
    }

    // stage X tile fp32 -> bf16 (4096 float4), 4 iters
    const float4* X4 = (const float4*)X;
    ushort4* Xl4 = (ushort4*)Xl;
#pragma unroll
    for (int i = t; i < 4096; i += 1024) {
        int r = i >> 5, c = i & 31;
        int gr = row0 + r;
        float4 v = make_float4(0.f, 0.f, 0.f, 0.f);
        if (gr < nRows) v = X4[(size_t)gr * 32 + c];
        ushort4 p;
        p.x = f2bf(v.x); p.y = f2bf(v.y); p.z = f2bf(v.z); p.w = f2bf(v.w);
        Xl4[r * (XSTR / 4) + c] = p;
    }
    __syncthreads();

    // 16 waves: wave w -> row tile (w&7)*16..+15, nt quad (w>>3)*4..+3
    const int wv = t >> 6, lane = t & 63;
    const int m = lane & 15, quad = lane >> 4;
    const int m0  = (wv & 7) << 4;
    const int nt0 = (wv >> 3) << 2;

    f32x4 acc[4];
    f32x4 z = {0.f, 0.f, 0.f, 0.f};
#pragma unroll
    for (int nt = 0; nt < 4; ++nt) acc[nt] = z;

#pragma unroll
    for (int kc = 0; kc < 4; ++kc) {
        bf16x8 a = *(const bf16x8*)(Xl + (m0 + m) * XSTR + kc * 32 + quad * 8);
#pragma unroll
        for (int nt = 0; nt < 4; ++nt) {
            bf16x8 b = *(const bf16x8*)(Wl + ((nt0 + nt) * 16 + m) * XSTR + kc * 32 + quad * 8);
            acc[nt] = __builtin_amdgcn_mfma_f32_16x16x32_bf16(a, b, acc[nt], 0, 0, 0);
        }
    }

    // row abs-max: each lane contributes max over its 4 nt per r
#pragma unroll
    for (int r = 0; r < 4; ++r) {
        float lm = fabsf(acc[0][r]);
        lm = fmaxf(lm, fabsf(acc[1][r]));
        lm = fmaxf(lm, fabsf(acc[2][r]));
        lm = fmaxf(lm, fabsf(acc[3][r]));
        atomicMax(&rowAmaxI[m0 + quad * 4 + r], __float_as_int(lm));
    }
    __syncthreads();

    // quantize: q = rn(acc * 127/rowmax) + 128; store int8 + per-row scale
#pragma unroll
    for (int r = 0; r < 4; ++r) {
        const int row = m0 + quad * 4 + r;
        const int gr = row0 + row;
        const float rm = __int_as_float(rowAmaxI[row]);
        const float inv = rm > 0.f ? 127.f / rm : 0.f;
        if (gr < nRows) {
#pragma unroll
            for (int nt = 0; nt < 4; ++nt) {
                int q = __float2int_rn(acc[nt][r] * inv) + 128;
                S8[(size_t)gr * D + (nt0 + nt) * 16 + m] = (unsigned char)q;
            }
            if (m == 0 && nt0 == 0)
                scaleArr[gr] = rm * (1.f / 127.f);
        }
    }
}

__device__ void fill2_path(const int* __restrict__ src,
                           const int* __restrict__ dst,
                           const float* __restrict__ vals,
                           int* gcursor, int2* __restrict__ epk,
                           int E, int nb, int blk, char* smem) {
    int* h   = (int*)smem;                  // [MAXB]
    int* cur = (int*)(smem + MAXB * 4);     // [MAXB]
    const int t = threadIdx.x;              // 0..1023
    for (int i = t; i < nb; i += 1024) h[i] = 0;
    __syncthreads();

    int chunk = (E + NFILL - 1) / NFILL;
    chunk = (chunk + 3) & ~3;                     // keep int4 alignment
    const int s0 = min(E, blk * chunk);
    const int s1 = min(E, s0 + chunk);
    const int vend = s0 + ((s1 - s0) & ~3);       // int4 region

    // single pass: stage this thread's edges (<=2 int4 groups) in regs
    const int e0 = s0 + (t << 2);
    const int e1 = e0 + 4096;
    int4 rs0, rd0, rs1, rd1;
    float4 rv0, rv1;
    const bool has0 = (e0 + 4 <= vend);
    const bool has1 = (e1 + 4 <= vend);
    if (has0) {
        rd0 = *(const int4*)(dst + e0);
        rs0 = *(const int4*)(src + e0);
        rv0 = *(const float4*)(vals + e0);
        atomicAdd(&h[rd0.x >> NB_SHIFT], 1);
        atomicAdd(&h[rd0.y >> NB_SHIFT], 1);
        atomicAdd(&h[rd0.z >> NB_SHIFT], 1);
        atomicAdd(&h[rd0.w >> NB_SHIFT], 1);
    }
    if (has1) {
        rd1 = *(const int4*)(dst + e1);
        rs1 = *(const int4*)(src + e1);
        rv1 = *(const float4*)(vals + e1);
        atomicAdd(&h[rd1.x >> NB_SHIFT], 1);
        atomicAdd(&h[rd1.y >> NB_SHIFT], 1);
        atomicAdd(&h[rd1.z >> NB_SHIFT], 1);
        atomicAdd(&h[rd1.w >> NB_SHIFT], 1);
    }
    for (int e = vend + t; e < s1; e += 1024)
        atomicAdd(&h[dst[e] >> NB_SHIFT], 1);
    __syncthreads();

    for (int i = t; i < nb; i += 1024) {
        int c = h[i];
        cur[i] = c ? (i * CAPB + atomicAdd(&gcursor[i], c)) : 0;
    }
    __syncthreads();

    if (has0) {
        int p0 = atomicAdd(&cur[rd0.x >> NB_SHIFT], 1);
        int p1 = atomicAdd(&cur[rd0.y >> NB_SHIFT], 1);
        int p2 = atomicAdd(&cur[rd0.z >> NB_SHIFT], 1);
        int p3 = atomicAdd(&cur[rd0.w >> NB_SHIFT], 1);
        epk[p0] = make_int2(rs0.x | ((rd0.x & (BNODES - 1)) << 20), __float_as_int(rv0.x));
        epk[p1] = make_int2(rs0.y | ((rd0.y & (BNODES - 1)) << 20), __float_as_int(rv0.y));
        epk[p2] = make_int2(rs0.z | ((rd0.z & (BNODES - 1)) << 20), __float_as_int(rv0.z));
        epk[p3] = make_int2(rs0.w | ((rd0.w & (BNODES - 1)) << 20), __float_as_int(rv0.w));
    }
    if (has1) {
        int p0 = atomicAdd(&cur[rd1.x >> NB_SHIFT], 1);
        int p1 = atomicAdd(&cur[rd1.y >> NB_SHIFT], 1);
        int p2 = atomicAdd(&cur[rd1.z >> NB_SHIFT], 1);
        int p3 = atomicAdd(&cur[rd1.w >> NB_SHIFT], 1);
        epk[p0] = make_int2(rs1.x | ((rd1.x & (BNODES - 1)) << 20), __float_as_int(rv1.x));
        epk[p1] = make_int2(rs1.y | ((rd1.y & (BNODES - 1)) << 20), __float_as_int(rv1.y));
        epk[p2] = make_int2(rs1.z | ((rd1.z & (BNODES - 1)) << 20), __float_as_int(rv1.z));
        epk[p3] = make_int2(rs1.w | ((rd1.w & (BNODES - 1)) << 20), __float_as_int(rv1.w));
    }
    for (int e = vend + t; e < s1; e += 1024) {
        int d = dst[e];
        int pos = atomicAdd(&cur[d >> NB_SHIFT], 1);
        epk[pos] = make_int2(src[e] | ((d & (BNODES - 1)) << 20), __float_as_int(vals[e]));
    }
}

__global__ __launch_bounds__(1024, 8) void fused_pre(const float* __restrict__ X,
                                                     const unsigned short* __restrict__ WT,
                                                     unsigned char* __restrict__ S8,
                                                     float* __restrict__ scaleArr,
                                                     int nRows,
                                                     const int* __restrict__ src,
                                                     const int* __restrict__ dst,
                                                     const float* __restrict__ vals,
                                                     int* gcursor, int2* __restrict__ epk,
                                                     int E, int nb) {
    __shared__ char smem[SMEM_BYTES];
    const int bid = blockIdx.x;
    if (bid < NFILL)
        fill2_path(src, dst, vals, gcursor, epk, E, nb, bid, smem);
    else
        gemm_path(X, WT, S8, scaleArr, nRows, bid - NFILL, smem);
}

// ---------------- bucket_gather: int8 support, col-split, XCD-paired halves ----------------
// bid = (b>>3)*16 + (b&7) + (h<<3): both halves of bucket b share bid%8 slot.
// Per-lane load = uint2 (8B); dequant a_k = sum(vs*q) - 128*sum(vs).
#define ACCQ(vs, mm) {                                                        \
    a[0] = fmaf(vs, (float)((mm.x) & 0xffu), a[0]);                           \
    a[1] = fmaf(vs, (float)((mm.x >> 8) & 0xffu), a[1]);                      \
    a[2] = fmaf(vs, (float)((mm.x >> 16) & 0xffu), a[2]);                     \
    a[3] = fmaf(vs, (float)(mm.x >> 24), a[3]);                               \
    a[4] = fmaf(vs, (float)((mm.y) & 0xffu), a[4]);                           \
    a[5] = fmaf(vs, (float)((mm.y >> 8) & 0xffu), a[5]);                      \
    a[6] = fmaf(vs, (float)((mm.y >> 16) & 0xffu), a[6]);                     \
    a[7] = fmaf(vs, (float)(mm.y >> 24), a[7]); }

__global__ __launch_bounds__(256, 8) void bucket_gather(const unsigned char* __restrict__ S8,
                                                        const float* __restrict__ scaleArr,
                                                        const int* __restrict__ gcursor,
                                                        const int2* __restrict__ epk,
                                                        float* __restrict__ out, int N, int nb) {
    __shared__ int2 se[CAPB];       // 11.3 KB
    __shared__ int  hist[BNODES];
    __shared__ int  rows[BNODES];
    __shared__ int  cur[BNODES];

    const int t    = threadIdx.x;
    const int grp  = blockIdx.x >> 4;
    const int rem  = blockIdx.x & 15;
    const int half = rem >> 3;                  // 0: cols 0-63, 1: 64-127
    const int b    = (grp << 3) + (rem & 7);    // bucket
    if (b >= nb) return;
    const int cnt  = min(gcursor[b], CAPB);
    const int beg  = b * CAPB;

    if (t < BNODES) hist[t] = 0;
    __syncthreads();

    // stage this thread's edges in registers: ONE global epk read total
    int2 r[RPT];
#pragma unroll
    for (int i = 0; i < RPT; ++i) {
        int idx = t + (i << 8);
        if (idx < cnt) r[i] = epk[beg + idx];
    }
#pragma unroll
    for (int i = 0; i < RPT; ++i) {
        int idx = t + (i << 8);
        if (idx < cnt) atomicAdd(&hist[(r[i].x >> 20) & (BNODES - 1)], 1);
    }
    __syncthreads();

    // Hillis-Steele inclusive scan of 64 counters
    if (t < BNODES) rows[t] = hist[t];
    __syncthreads();
#pragma unroll
    for (int off = 1; off < BNODES; off <<= 1) {
        int v = 0;
        if (t < BNODES && t >= off) v = rows[t - off];
        __syncthreads();
        if (t < BNODES && t >= off) rows[t] += v;
        __syncthreads();
    }
    if (t < BNODES) cur[t] = rows[t] - hist[t];
    __syncthreads();

    // scatter registers into sorted LDS order
#pragma unroll
    for (int i = 0; i < RPT; ++i) {
        int idx = t + (i << 8);
        if (idx < cnt) {
            int pos = atomicAdd(&cur[(r[i].x >> 20) & (BNODES - 1)], 1);
            se[pos] = r[i];
        }
    }
    __syncthreads();

    // per-node accumulation: group g (8 lanes) handles nodes g, g+32
    const int g = t >> 3, lane = t & 7;
    const int node0 = b << NB_SHIFT;
    const int cb = (half << 6) + (lane << 3);    // byte offset within support row
    float4* o4 = (float4*)out;

#pragma unroll
    for (int nn = g; nn < BNODES; nn += 32) {
        const int send = rows[nn];
        const int sbeg = send - hist[nn];

        float a[8];
#pragma unroll
        for (int k = 0; k < 8; ++k) a[k] = 0.f;
        float svs = 0.f;

        int j = sbeg;
        for (; j + 4 <= send; j += 4) {          // 4 outstanding 64 B row-half gathers
            int2 e0 = se[j], e1 = se[j + 1], e2 = se[j + 2], e3 = se[j + 3];
            const int s0i = e0.x & 0xFFFFF, s1i = e1.x & 0xFFFFF;
            const int s2i = e2.x & 0xFFFFF, s3i = e3.x & 0xFFFFF;
            uint2 m0 = *(const uint2*)(S8 + ((size_t)s0i << 7) + cb);
            uint2 m1 = *(const uint2*)(S8 + ((size_t)s1i << 7) + cb);
            uint2 m2 = *(const uint2*)(S8 + ((size_t)s2i << 7) + cb);
            uint2 m3 = *(const uint2*)(S8 + ((size_t)s3i << 7) + cb);
            float vs0 = __int_as_float(e0.y) * scaleArr[s0i];
            float vs1 = __int_as_float(e1.y) * scaleArr[s1i];
            float vs2 = __int_as_float(e2.y) * scaleArr[s2i];
            float vs3 = __int_as_float(e3.y) * scaleArr[s3i];
            svs += (vs0 + vs1) + (vs2 + vs3);
            ACCQ(vs0, m0); ACCQ(vs1, m1); ACCQ(vs2, m2); ACCQ(vs3, m3);
        }
        for (; j < send; ++j) {
            int2 e0 = se[j];
            const int s0i = e0.x & 0xFFFFF;
            uint2 m0 = *(const uint2*)(S8 + ((size_t)s0i << 7) + cb);
            float vs0 = __int_as_float(e0.y) * scaleArr[s0i];
            svs += vs0;
            ACCQ(vs0, m0);
        }

        // remove the +128 bias: a_k -= 128 * sum(vs)
#pragma unroll
        for (int k = 0; k < 8; ++k) a[k] = fmaf(-128.f, svs, a[k]);

        const int gn = node0 + nn;
        if (gn < N) {
            size_t base = (size_t)gn * 32 + (half << 4) + 2 * lane;
            float4 lo = make_float4(fmaxf(a[0], 0.f), fmaxf(a[1], 0.f),
                                    fmaxf(a[2], 0.f), fmaxf(a[3], 0.f));
            float4 hi = make_float4(fmaxf(a[4], 0.f), fmaxf(a[5], 0.f),
                                    fmaxf(a[6], 0.f), fmaxf(a[7], 0.f));
            o4[base]     = lo;
            o4[base + 1] = hi;
        }
    }
}

extern "C" void kernel_launch(void* const* d_in, const int* in_sizes, int n_in,
                              void* d_out, int out_size, void* d_ws, size_t ws_size,
                              hipStream_t stream) {
    const float* X    = (const float*)d_in[0];
    const float* W    = (const float*)d_in[1];
    const float* vals = (const float*)d_in[2];
    const int*   src  = (const int*)d_in[3];
    const int*   dst  = (const int*)d_in[4];
    float*       out  = (float*)d_out;

    const int N  = in_sizes[0] / D;
    const int E  = in_sizes[2];
    const int nb = (N + BNODES - 1) / BNODES;   // 1563

    size_t off = 0;
    auto take = [&](size_t bytes) {
        size_t p = off;
        off = (off + bytes + 255) & ~(size_t)255;
        return p;
    };
    char* ws = (char*)d_ws;
    size_t o_support = take((size_t)N * D);                 // int8
    size_t o_scale   = take((size_t)N * sizeof(float));
    size_t o_wt      = take((size_t)D * D * sizeof(unsigned short));
    size_t o_cursor  = take((size_t)nb * sizeof(int));
    size_t o_epk     = take(((size_t)nb * CAPB + 1024) * sizeof(int2));
    (void)ws_size;

    unsigned char*  S8       = (unsigned char*)(ws + o_support);
    float*          scaleArr = (float*)(ws + o_scale);
    unsigned short* WT       = (unsigned short*)(ws + o_wt);
    int*  cursor = (int*)(ws + o_cursor);
    int2* epk    = (int2*)(ws + o_epk);

    // 1) WT = bf16(W^T); zero bucket cursors
    wtrans<<<8, 256, 0, stream>>>(W, WT, cursor, nb);

    // 2) fused: fill2 (blocks 0..255) || gemm (blocks 256..256+nbG-1)
    const int nbG = (N + GROWS - 1) / GROWS;    // 782
    fused_pre<<<NFILL + nbG, 1024, 0, stream>>>(X, WT, S8, scaleArr, N,
                                                src, dst, vals, cursor, epk, E, nb);

    // 3) gather: halves of bucket b share XCD slot; grid = ceil(nb/8)*16
    const int gblocks = ((nb + 7) / 8) * 16;
    bucket_gather<<<gblocks, 256, 0, stream>>>(S8, scaleArr, cursor, epk, out, N, nb);
}